// Round 10
// baseline (10766.048 us; speedup 1.0000x reference)
//
#include <hip/hip_runtime.h>
#include <hip/hip_bf16.h>
#include <math.h>

#define Tn   2048
#define Cn   1536
#define Vn   32000
#define NHn  12
#define NKVn 4
#define Dn   128
#define HIDn 2048
#define En   8
#define Kn   2
#define Ln   2
#define NREPn 3
#define EPSn 1e-6f

using bf16 = __hip_bfloat16;
using bf16x8 = __attribute__((ext_vector_type(8))) short;
using f32x4v = __attribute__((ext_vector_type(4))) float;

// Exact 3-way bf16 split: v = hi + mid + lo + O(2^-27 * v)
__device__ __forceinline__ void split3(float v, short& h, short& m, short& lo) {
  bf16 b0 = __float2bfloat16(v);
  float r1 = v - __bfloat162float(b0);
  bf16 b1 = __float2bfloat16(r1);
  float r2 = r1 - __bfloat162float(b1);
  bf16 b2 = __float2bfloat16(r2);
  h = *reinterpret_cast<short*>(&b0);
  m = *reinterpret_cast<short*>(&b1);
  lo = *reinterpret_cast<short*>(&b2);
}

// ---------------- embed (validated) ----------------
__global__ void embed_k(const int* __restrict__ tok, const float* __restrict__ emb,
                        const float* __restrict__ pos, float* __restrict__ x) {
  int n = blockIdx.x;
  int t = threadIdx.x;
  int id = tok[n];
  const float* er = emb + (size_t)id * Cn;
  const float* pr = pos + (size_t)n * Cn;
  float* xr = x + (size_t)n * Cn;
  for (int c = t; c < Cn; c += 256) xr[c] = er[c] + pr[c];
}

// ---------------- RMSNorm fp32 (validated) ----------------
__global__ void rmsnorm_k(const float* __restrict__ x, const float* __restrict__ w,
                          float* __restrict__ out) {
  int n = blockIdx.x, t = threadIdx.x;
  const float* xr = x + (size_t)n * Cn;
  float v[6];
  float ss = 0.f;
#pragma unroll
  for (int i = 0; i < 6; i++) { v[i] = xr[t + i * 256]; ss += v[i] * v[i]; }
  for (int off = 32; off > 0; off >>= 1) ss += __shfl_down(ss, off, 64);
  __shared__ float red[4];
  __shared__ float rtot;
  int wave = t >> 6, lane = t & 63;
  if (lane == 0) red[wave] = ss;
  __syncthreads();
  if (t == 0) rtot = rsqrtf((red[0] + red[1] + red[2] + red[3]) / (float)Cn + EPSn);
  __syncthreads();
  float r = rtot;
  float* orow = out + (size_t)n * Cn;
#pragma unroll
  for (int i = 0; i < 6; i++) { int c = t + i * 256; orow[c] = v[i] * r * w[c]; }
}

// ---------------- fp32 -> bf16 (validated) ----------------
__global__ void f2b_k(const float* __restrict__ s, bf16* __restrict__ d, size_t n4) {
  size_t i = (size_t)blockIdx.x * 256 + threadIdx.x;
  size_t stride = (size_t)gridDim.x * 256;
  for (; i < n4; i += stride) {
    float4 v = ((const float4*)s)[i];
    d[i * 4 + 0] = __float2bfloat16(v.x);
    d[i * 4 + 1] = __float2bfloat16(v.y);
    d[i * 4 + 2] = __float2bfloat16(v.z);
    d[i * 4 + 3] = __float2bfloat16(v.w);
  }
}

// ---------------- NEW: transpose + 3-way split: f32 [K,N] -> 3x bf16 [N,K] (batched z) ----------------
__global__ void transp3_k(const float* __restrict__ src, short* __restrict__ dh,
                          short* __restrict__ dm, short* __restrict__ dl, int K, int N) {
  __shared__ __align__(16) float ls[32][33];
  size_t boff = (size_t)blockIdx.z * K * N;
  int k0 = blockIdx.x * 32, n0 = blockIdx.y * 32;
  int t = threadIdx.x;
  int kr = t >> 3, n4 = (t & 7) * 4;
  float4 vv = *(const float4*)&src[boff + (size_t)(k0 + kr) * N + n0 + n4];
  ls[kr][n4 + 0] = vv.x; ls[kr][n4 + 1] = vv.y; ls[kr][n4 + 2] = vv.z; ls[kr][n4 + 3] = vv.w;
  __syncthreads();
  int nr = t >> 3, k4 = (t & 7) * 4;
  size_t dbase = boff + (size_t)(n0 + nr) * K + k0 + k4;
#pragma unroll
  for (int u = 0; u < 4; u++) {
    short h, m, lo;
    split3(ls[k4 + u][nr], h, m, lo);
    dh[dbase + u] = h; dm[dbase + u] = m; dl[dbase + u] = lo;
  }
}

// ---------------- MFMA GEMM pure bf16, Bt [N,K] (validated, logits tail only) ----------------
__global__ void __launch_bounds__(256) gemm_bt(const bf16* __restrict__ A, const bf16* __restrict__ Bt,
                                               const float* res, float* Co, int M, int N, int K) {
  int t = threadIdx.x;
  int l = t & 63, w = t >> 6;
  int bm = blockIdx.x * 128, bn = blockIdx.y * 128;
  int wr = (w >> 1) * 64, wc = (w & 1) * 64;
  const f32x4v zero = {0.f, 0.f, 0.f, 0.f};
  f32x4v acc[4][4];
#pragma unroll
  for (int i = 0; i < 4; i++)
#pragma unroll
    for (int j = 0; j < 4; j++) acc[i][j] = zero;
  int rl = l & 15, kg = (l >> 4) * 8;
  const bf16* arow[4];
  const bf16* brow[4];
#pragma unroll
  for (int i = 0; i < 4; i++) arow[i] = A + (size_t)(bm + wr + i * 16 + rl) * K + kg;
#pragma unroll
  for (int j = 0; j < 4; j++) brow[j] = Bt + (size_t)(bn + wc + j * 16 + rl) * K + kg;
  for (int k0 = 0; k0 < K; k0 += 32) {
    bf16x8 a[4], b[4];
#pragma unroll
    for (int i = 0; i < 4; i++) a[i] = *(const bf16x8*)(arow[i] + k0);
#pragma unroll
    for (int j = 0; j < 4; j++) b[j] = *(const bf16x8*)(brow[j] + k0);
#pragma unroll
    for (int i = 0; i < 4; i++)
#pragma unroll
      for (int j = 0; j < 4; j++)
        acc[i][j] = __builtin_amdgcn_mfma_f32_16x16x32_bf16(a[i], b[j], acc[i][j], 0, 0, 0);
  }
#pragma unroll
  for (int i = 0; i < 4; i++) {
    int rbase = bm + wr + i * 16 + (l >> 4) * 4;
#pragma unroll
    for (int j = 0; j < 4; j++) {
      int col = bn + wc + j * 16 + (l & 15);
#pragma unroll
      for (int r = 0; r < 4; r++) {
        size_t idx = (size_t)(rbase + r) * N + col;
        float v = acc[i][j][r];
        if (res) v += res[idx];
        Co[idx] = v;
      }
    }
  }
}

// ---------------- split-fp32 GEMM, pre-split B: A f32 [M,K], Bt hi/mid/lo bf16 [N,K] (+res) ----------------
// Same 6 MFMA products as round 8/9 (bitwise identical), B loads coalesced bf16x8.
__global__ void __launch_bounds__(256) gemm_bs6(const float* __restrict__ A,
                                                const short* __restrict__ BtH,
                                                const short* __restrict__ BtM,
                                                const short* __restrict__ BtL,
                                                const float* res, float* __restrict__ Co,
                                                int M, int N, int K) {
  int t = threadIdx.x;
  int l = t & 63, w = t >> 6;
  int bm = blockIdx.x * 128, bn = blockIdx.y * 128;
  int wr = (w >> 1) * 64, wc = (w & 1) * 64;
  const f32x4v zero = {0.f, 0.f, 0.f, 0.f};
  f32x4v acc[4][4];
#pragma unroll
  for (int i = 0; i < 4; i++)
#pragma unroll
    for (int j = 0; j < 4; j++) acc[i][j] = zero;
  int rl = l & 15, kg = (l >> 4) * 8;
  const float* arow[4];
  size_t boff[4];
#pragma unroll
  for (int i = 0; i < 4; i++) arow[i] = A + (size_t)(bm + wr + i * 16 + rl) * K + kg;
#pragma unroll
  for (int j = 0; j < 4; j++) boff[j] = (size_t)(bn + wc + j * 16 + rl) * K + kg;
  for (int k0 = 0; k0 < K; k0 += 32) {
    bf16x8 aH[4], aM[4], aL[4], bH[4], bM[4], bL[4];
#pragma unroll
    for (int i = 0; i < 4; i++) {
      float4 u = *(const float4*)(arow[i] + k0);
      float4 v = *(const float4*)(arow[i] + k0 + 4);
      float av[8] = {u.x, u.y, u.z, u.w, v.x, v.y, v.z, v.w};
#pragma unroll
      for (int jj = 0; jj < 8; jj++) {
        short sh, sm, sl;
        split3(av[jj], sh, sm, sl);
        aH[i][jj] = sh; aM[i][jj] = sm; aL[i][jj] = sl;
      }
    }
#pragma unroll
    for (int j = 0; j < 4; j++) {
      bH[j] = *(const bf16x8*)(BtH + boff[j] + k0);
      bM[j] = *(const bf16x8*)(BtM + boff[j] + k0);
      bL[j] = *(const bf16x8*)(BtL + boff[j] + k0);
    }
#pragma unroll
    for (int i = 0; i < 4; i++)
#pragma unroll
      for (int j = 0; j < 4; j++) {
        acc[i][j] = __builtin_amdgcn_mfma_f32_16x16x32_bf16(aL[i], bH[j], acc[i][j], 0, 0, 0);
        acc[i][j] = __builtin_amdgcn_mfma_f32_16x16x32_bf16(aH[i], bL[j], acc[i][j], 0, 0, 0);
        acc[i][j] = __builtin_amdgcn_mfma_f32_16x16x32_bf16(aM[i], bM[j], acc[i][j], 0, 0, 0);
        acc[i][j] = __builtin_amdgcn_mfma_f32_16x16x32_bf16(aM[i], bH[j], acc[i][j], 0, 0, 0);
        acc[i][j] = __builtin_amdgcn_mfma_f32_16x16x32_bf16(aH[i], bM[j], acc[i][j], 0, 0, 0);
        acc[i][j] = __builtin_amdgcn_mfma_f32_16x16x32_bf16(aH[i], bH[j], acc[i][j], 0, 0, 0);
      }
  }
#pragma unroll
  for (int i = 0; i < 4; i++) {
    int rbase = bm + wr + i * 16 + (l >> 4) * 4;
#pragma unroll
    for (int j = 0; j < 4; j++) {
      int col = bn + wc + j * 16 + (l & 15);
#pragma unroll
      for (int r = 0; r < 4; r++) {
        size_t idx = (size_t)(rbase + r) * N + col;
        float v = acc[i][j][r];
        if (res) v += res[idx];
        Co[idx] = v;
      }
    }
  }
}

// ---------------- split-fp32 MoE expert GEMM, pre-split transposed B (gathered A rows) ----------------
// mode 0: out = silu(acc); mode 1: out *= acc; mode 2: out = acc
__global__ void __launch_bounds__(256) mexp_bs6(const float* __restrict__ Abase,
                                                const short* __restrict__ BH,
                                                const short* __restrict__ BM,
                                                const short* __restrict__ BL,
                                                const int* __restrict__ perm, const int* __restrict__ cnt,
                                                float* __restrict__ Out, int K, int N, int mode) {
  int e = blockIdx.z;
  int nrows = cnt[e];
  int bm = blockIdx.x * 128;
  if (bm >= nrows) return;
  int bn = blockIdx.y * 128;
  size_t eoff = (size_t)e * K * N;
  __shared__ int prow[128];
  int t = threadIdx.x, l = t & 63, w = t >> 6;
  if (t < 128) {
    int i = bm + t;
    prow[t] = (i < nrows) ? perm[e * Tn + i] : -1;
  }
  __syncthreads();
  int wr = (w >> 1) * 64, wc = (w & 1) * 64;
  const f32x4v zero = {0.f, 0.f, 0.f, 0.f};
  f32x4v acc[4][4];
#pragma unroll
  for (int i = 0; i < 4; i++)
#pragma unroll
    for (int j = 0; j < 4; j++) acc[i][j] = zero;
  int rl = l & 15, kg = (l >> 4) * 8;
  const float* arow[4];
  size_t boff[4];
#pragma unroll
  for (int i = 0; i < 4; i++) {
    int p = prow[wr + i * 16 + rl];
    int ar = (p >= 0) ? (mode == 2 ? p : (p >> 1)) : 0;
    arow[i] = Abase + (size_t)ar * K + kg;
  }
#pragma unroll
  for (int j = 0; j < 4; j++) boff[j] = eoff + (size_t)(bn + wc + j * 16 + rl) * K + kg;
  for (int k0 = 0; k0 < K; k0 += 32) {
    bf16x8 aH[4], aM[4], aL[4], bH[4], bM[4], bL[4];
#pragma unroll
    for (int i = 0; i < 4; i++) {
      float4 u = *(const float4*)(arow[i] + k0);
      float4 v = *(const float4*)(arow[i] + k0 + 4);
      float av[8] = {u.x, u.y, u.z, u.w, v.x, v.y, v.z, v.w};
#pragma unroll
      for (int jj = 0; jj < 8; jj++) {
        short sh, sm, sl;
        split3(av[jj], sh, sm, sl);
        aH[i][jj] = sh; aM[i][jj] = sm; aL[i][jj] = sl;
      }
    }
#pragma unroll
    for (int j = 0; j < 4; j++) {
      bH[j] = *(const bf16x8*)(BH + boff[j] + k0);
      bM[j] = *(const bf16x8*)(BM + boff[j] + k0);
      bL[j] = *(const bf16x8*)(BL + boff[j] + k0);
    }
#pragma unroll
    for (int i = 0; i < 4; i++)
#pragma unroll
      for (int j = 0; j < 4; j++) {
        acc[i][j] = __builtin_amdgcn_mfma_f32_16x16x32_bf16(aL[i], bH[j], acc[i][j], 0, 0, 0);
        acc[i][j] = __builtin_amdgcn_mfma_f32_16x16x32_bf16(aH[i], bL[j], acc[i][j], 0, 0, 0);
        acc[i][j] = __builtin_amdgcn_mfma_f32_16x16x32_bf16(aM[i], bM[j], acc[i][j], 0, 0, 0);
        acc[i][j] = __builtin_amdgcn_mfma_f32_16x16x32_bf16(aM[i], bH[j], acc[i][j], 0, 0, 0);
        acc[i][j] = __builtin_amdgcn_mfma_f32_16x16x32_bf16(aH[i], bM[j], acc[i][j], 0, 0, 0);
        acc[i][j] = __builtin_amdgcn_mfma_f32_16x16x32_bf16(aH[i], bH[j], acc[i][j], 0, 0, 0);
      }
  }
#pragma unroll
  for (int i = 0; i < 4; i++) {
#pragma unroll
    for (int r = 0; r < 4; r++) {
      int lrow = wr + i * 16 + (l >> 4) * 4 + r;
      int p = prow[lrow];
      if (p < 0) continue;
#pragma unroll
      for (int j = 0; j < 4; j++) {
        int col = bn + wc + j * 16 + (l & 15);
        size_t idx = (size_t)p * N + col;
        float v = acc[i][j][r];
        if (mode == 0) {
          Out[idx] = v / (1.f + expf(-v));
        } else if (mode == 1) {
          Out[idx] *= v;
        } else {
          Out[idx] = v;
        }
      }
    }
  }
}

// ---------------- register-resident fp32 flash attention (validated round 9) ----------------
__global__ void __launch_bounds__(256) attn_fast_k(const float* __restrict__ q,
                                                   const float* __restrict__ k,
                                                   const float* __restrict__ v,
                                                   float* __restrict__ y) {
  int qt = blockIdx.x, head = blockIdx.y;
  int kvh = head / NREPn;
  int q0 = qt * 32;
  int t = threadIdx.x;
  int r = t >> 3, g = t & 7, d0 = g * 16;
  __shared__ __align__(16) float ks[32][Dn + 4];
  __shared__ __align__(16) float vs[32][Dn + 4];
  const float scale = 0.08838834764831845f;
  float qr[16];
  {
    const float* qrow = q + (size_t)(q0 + r) * (NHn * Dn) + head * Dn + d0;
#pragma unroll
    for (int j = 0; j < 16; j += 4) {
      float4 u = *(const float4*)(qrow + j);
      qr[j] = u.x * scale; qr[j + 1] = u.y * scale;
      qr[j + 2] = u.z * scale; qr[j + 3] = u.w * scale;
    }
  }
  float o[16];
#pragma unroll
  for (int j = 0; j < 16; j++) o[j] = 0.f;
  float rowm = -1e30f, rowl = 0.f;

  for (int kt = 0; kt <= qt; kt++) {
    int kv0 = kt * 32;
    for (int e = t; e < 32 * 32; e += 256) {
      int rr = e >> 5, c4 = (e & 31) * 4;
      size_t off = (size_t)(kv0 + rr) * (NKVn * Dn) + kvh * Dn + c4;
      *(float4*)&ks[rr][c4] = *(const float4*)(k + off);
      *(float4*)&vs[rr][c4] = *(const float4*)(v + off);
    }
    __syncthreads();
    float s[32];
#pragma unroll
    for (int kk = 0; kk < 32; kk++) {
      const float* krow = &ks[kk][d0];
      float p = 0.f;
#pragma unroll
      for (int j = 0; j < 16; j += 4) {
        float4 u = *(const float4*)(krow + j);
        p += qr[j] * u.x + qr[j + 1] * u.y + qr[j + 2] * u.z + qr[j + 3] * u.w;
      }
      p += __shfl_xor(p, 1);
      p += __shfl_xor(p, 2);
      p += __shfl_xor(p, 4);
      s[kk] = p;
    }
    if (kt == qt) {
#pragma unroll
      for (int kk = 0; kk < 32; kk++)
        if (kk > r) s[kk] = -1e30f;
    }
    float mx = s[0];
#pragma unroll
    for (int kk = 1; kk < 32; kk++) mx = fmaxf(mx, s[kk]);
    float m_new = fmaxf(rowm, mx);
    float corr = expf(rowm - m_new);
    float sum = 0.f;
#pragma unroll
    for (int kk = 0; kk < 32; kk++) { s[kk] = expf(s[kk] - m_new); sum += s[kk]; }
    rowl = rowl * corr + sum;
    rowm = m_new;
#pragma unroll
    for (int j = 0; j < 16; j++) o[j] *= corr;
#pragma unroll
    for (int kk = 0; kk < 32; kk++) {
      float p = s[kk];
      const float* vrow = &vs[kk][d0];
#pragma unroll
      for (int j = 0; j < 16; j += 4) {
        float4 u = *(const float4*)(vrow + j);
        o[j] += p * u.x; o[j + 1] += p * u.y; o[j + 2] += p * u.z; o[j + 3] += p * u.w;
      }
    }
    __syncthreads();
  }
  float inv = 1.f / rowl;
  float* yrow = y + (size_t)(q0 + r) * (NHn * Dn) + head * Dn + d0;
#pragma unroll
  for (int j = 0; j < 16; j += 4) {
    float4 u;
    u.x = o[j] * inv; u.y = o[j + 1] * inv; u.z = o[j + 2] * inv; u.w = o[j + 3] * inv;
    *(float4*)(yrow + j) = u;
  }
}

// ---------------- gate logits (validated) ----------------
__global__ void gate_k(const float* __restrict__ xf, const float* __restrict__ g,
                       float* __restrict__ gl) {
  int n = blockIdx.x, t = threadIdx.x;
  int e = t & 7, cs = t >> 3;
  const float* xr = xf + (size_t)n * Cn;
  float s = 0.f;
  for (int j = 0; j < Cn / 32; j++) {
    int c = cs + 32 * j;
    s += xr[c] * g[c * En + e];
  }
  __shared__ float red[256];
  red[t] = s;
  __syncthreads();
  if (t < 8) {
    float tot = 0.f;
    for (int j = 0; j < 32; j++) tot += red[t + 8 * j];
    gl[n * En + t] = tot;
  }
}

// ---------------- routing (validated, Tn stride) ----------------
__global__ void route_k(const float* __restrict__ gl, float* __restrict__ topw,
                        int* __restrict__ cnt, int* __restrict__ perm) {
  int n = blockIdx.x * blockDim.x + threadIdx.x;
  if (n >= Tn) return;
  float p[En];
  float mx = -1e30f;
#pragma unroll
  for (int e = 0; e < En; e++) { p[e] = gl[n * En + e]; mx = fmaxf(mx, p[e]); }
  float s = 0.f;
#pragma unroll
  for (int e = 0; e < En; e++) { p[e] = expf(p[e] - mx); s += p[e]; }
  float invs = 1.f / s;
#pragma unroll
  for (int e = 0; e < En; e++) p[e] *= invs;
  int i0 = 0;
#pragma unroll
  for (int e = 1; e < En; e++) if (p[e] > p[i0]) i0 = e;
  int i1 = (i0 == 0) ? 1 : 0;
#pragma unroll
  for (int e = 0; e < En; e++) if (e != i0 && p[e] > p[i1]) i1 = e;
  float w0 = p[i0], w1 = p[i1], sw = w0 + w1;
  topw[2 * n]     = w0 / sw;
  topw[2 * n + 1] = w1 / sw;
  int pos0 = atomicAdd(&cnt[i0], 1);
  perm[i0 * Tn + pos0] = 2 * n;
  int pos1 = atomicAdd(&cnt[i1], 1);
  perm[i1 * Tn + pos1] = 2 * n + 1;
}

// ---------------- combine (validated) ----------------
__global__ void combine_k(const float* __restrict__ pairout, const float* __restrict__ topw,
                          float* __restrict__ x) {
  int n = blockIdx.x, t = threadIdx.x;
  float w0 = topw[2 * n], w1 = topw[2 * n + 1];
  const float* p0 = pairout + (size_t)(2 * n) * Cn;
  const float* p1 = pairout + (size_t)(2 * n + 1) * Cn;
  float* xr = x + (size_t)n * Cn;
  for (int c = t; c < Cn; c += 256) xr[c] += w0 * p0[c] + w1 * p1[c];
}

// =================================================================================
extern "C" void kernel_launch(void* const* d_in, const int* in_sizes, int n_in,
                              void* d_out, int out_size, void* d_ws, size_t ws_size,
                              hipStream_t stream) {
  const int*   tokens = (const int*)d_in[0];
  const float* emb    = (const float*)d_in[1];
  const float* pos    = (const float*)d_in[2];
  const float* wq     = (const float*)d_in[3];
  const float* wk     = (const float*)d_in[4];
  const float* wv     = (const float*)d_in[5];
  const float* wo     = (const float*)d_in[6];
  const float* attn_nw= (const float*)d_in[7];
  const float* ffn_nw = (const float*)d_in[8];
  const float* gate   = (const float*)d_in[9];
  const float* ew1    = (const float*)d_in[10];
  const float* ew2    = (const float*)d_in[11];
  const float* ew3    = (const float*)d_in[12];
  const float* final_nw = (const float*)d_in[13];
  float* out = (float*)d_out;

  char* wsb = (char*)d_ws;
  const size_t NC = (size_t)Tn * Cn;
  size_t off = 0;
  auto alloc = [&](size_t bytes) -> size_t {
    off = (off + 255) & ~(size_t)255;
    size_t p = off;
    off += bytes;
    return p;
  };
  // Total ~250 MB; ws >= 264.4 MB proven (rounds 2-4 ran their fast path).
  size_t o_x    = alloc(NC * 4);
  size_t o_h    = alloc(NC * 4);
  size_t o_qb   = alloc(NC * 4);                       // pair aliases qb..yb in MoE phase
  size_t o_kb   = alloc((size_t)Tn * NKVn * Dn * 4);
  size_t o_vb   = alloc((size_t)Tn * NKVn * Dn * 4);
  size_t o_yb   = alloc(NC * 4);
  size_t o_gl   = alloc((size_t)Tn * En * 4);
  size_t o_topw = alloc((size_t)Tn * Kn * 4);
  size_t o_hbuf = alloc((size_t)Tn * Kn * HIDn * 4);   // fp32
  size_t o_cnt  = alloc(64);
  size_t o_perm = alloc((size_t)En * Tn * 4);
  size_t o_hb   = alloc(NC * 2);                       // logits-tail A (bf16)
  // weight-split region: reused attn(37.7MB) -> ew1 -> ew3 -> ew2 (151MB each) -> embB (98.3MB)
  size_t moe_lvl = (size_t)En * Cn * HIDn * 2;         // 50.33 MB per split level
  size_t o_wr   = alloc(3 * moe_lvl);                  // 151 MB

  float* x       = (float*)(wsb + o_x);
  float* h       = (float*)(wsb + o_h);
  float* qb      = (float*)(wsb + o_qb);
  float* kb      = (float*)(wsb + o_kb);
  float* vb      = (float*)(wsb + o_vb);
  float* yb      = (float*)(wsb + o_yb);
  float* gl      = (float*)(wsb + o_gl);
  float* topw    = (float*)(wsb + o_topw);
  float* hbuf    = (float*)(wsb + o_hbuf);
  int*   cnt     = (int*)(wsb + o_cnt);
  int*   perm    = (int*)(wsb + o_perm);
  bf16*  hb      = (bf16*)(wsb + o_hb);
  float* pairout = (float*)(wsb + o_qb);               // alias (MoE phase; qkv/yb dead)
  bf16*  embB    = (bf16*)(wsb + o_wr);                // alias (tail; weight splits dead)

  // attn weight splits inside the region
  size_t wq_sz = (size_t)Cn * (NHn * Dn) * 2;          // 4.72 MB per level
  size_t wk_sz = (size_t)Cn * (NKVn * Dn) * 2;         // 1.57 MB per level
  short* wqT[3]; short* wkT[3]; short* wvT[3]; short* woT[3]; short* ewT[3];
  {
    size_t p = o_wr;
    for (int s = 0; s < 3; s++) { wqT[s] = (short*)(wsb + p); p += wq_sz; }
    for (int s = 0; s < 3; s++) { wkT[s] = (short*)(wsb + p); p += wk_sz; }
    for (int s = 0; s < 3; s++) { wvT[s] = (short*)(wsb + p); p += wk_sz; }
    for (int s = 0; s < 3; s++) { woT[s] = (short*)(wsb + p); p += wq_sz; }
    for (int s = 0; s < 3; s++) ewT[s] = (short*)(wsb + o_wr + (size_t)s * moe_lvl);
  }

  embed_k<<<Tn, 256, 0, stream>>>(tokens, emb, pos, x);
  for (int l = 0; l < Ln; l++) {
    const float* wq_l = wq + (size_t)l * Cn * (NHn * Dn);
    const float* wk_l = wk + (size_t)l * Cn * (NKVn * Dn);
    const float* wv_l = wv + (size_t)l * Cn * (NKVn * Dn);
    const float* wo_l = wo + (size_t)l * Cn * Cn;
    const float* g_l  = gate + (size_t)l * Cn * En;
    const float* e1_l = ew1 + (size_t)l * En * Cn * HIDn;
    const float* e2_l = ew2 + (size_t)l * En * HIDn * Cn;
    const float* e3_l = ew3 + (size_t)l * En * Cn * HIDn;

    // --- attention: pre-split weights + split-fp32 MFMA + register-flash core ---
    transp3_k<<<dim3(Cn / 32, (NHn * Dn) / 32, 1), 256, 0, stream>>>(wq_l, wqT[0], wqT[1], wqT[2], Cn, NHn * Dn);
    transp3_k<<<dim3(Cn / 32, (NKVn * Dn) / 32, 1), 256, 0, stream>>>(wk_l, wkT[0], wkT[1], wkT[2], Cn, NKVn * Dn);
    transp3_k<<<dim3(Cn / 32, (NKVn * Dn) / 32, 1), 256, 0, stream>>>(wv_l, wvT[0], wvT[1], wvT[2], Cn, NKVn * Dn);
    transp3_k<<<dim3(Cn / 32, Cn / 32, 1), 256, 0, stream>>>(wo_l, woT[0], woT[1], woT[2], Cn, Cn);
    rmsnorm_k<<<Tn, 256, 0, stream>>>(x, attn_nw + (size_t)l * Cn, h);
    gemm_bs6<<<dim3(Tn / 128, (NHn * Dn) / 128), 256, 0, stream>>>(h, wqT[0], wqT[1], wqT[2], nullptr, qb, Tn, NHn * Dn, Cn);
    gemm_bs6<<<dim3(Tn / 128, (NKVn * Dn) / 128), 256, 0, stream>>>(h, wkT[0], wkT[1], wkT[2], nullptr, kb, Tn, NKVn * Dn, Cn);
    gemm_bs6<<<dim3(Tn / 128, (NKVn * Dn) / 128), 256, 0, stream>>>(h, wvT[0], wvT[1], wvT[2], nullptr, vb, Tn, NKVn * Dn, Cn);
    attn_fast_k<<<dim3(Tn / 32, NHn), 256, 0, stream>>>(qb, kb, vb, yb);
    gemm_bs6<<<dim3(Tn / 128, Cn / 128), 256, 0, stream>>>(yb, woT[0], woT[1], woT[2], x, x, Tn, Cn, Cn);

    // --- MoE: fp32 routing; expert GEMMs split-fp32 with pre-split transposed weights ---
    rmsnorm_k<<<Tn, 256, 0, stream>>>(x, ffn_nw + (size_t)l * Cn, h);
    gate_k<<<Tn, 256, 0, stream>>>(h, g_l, gl);
    hipMemsetAsync(cnt, 0, 64, stream);
    route_k<<<Tn / 256, 256, 0, stream>>>(gl, topw, cnt, perm);
    transp3_k<<<dim3(Cn / 32, HIDn / 32, En), 256, 0, stream>>>(e1_l, ewT[0], ewT[1], ewT[2], Cn, HIDn);
    mexp_bs6<<<dim3(Tn / 128, HIDn / 128, En), 256, 0, stream>>>(h, ewT[0], ewT[1], ewT[2], perm, cnt, hbuf, Cn, HIDn, 0);
    transp3_k<<<dim3(Cn / 32, HIDn / 32, En), 256, 0, stream>>>(e3_l, ewT[0], ewT[1], ewT[2], Cn, HIDn);
    mexp_bs6<<<dim3(Tn / 128, HIDn / 128, En), 256, 0, stream>>>(h, ewT[0], ewT[1], ewT[2], perm, cnt, hbuf, Cn, HIDn, 1);
    transp3_k<<<dim3(HIDn / 32, Cn / 32, En), 256, 0, stream>>>(e2_l, ewT[0], ewT[1], ewT[2], HIDn, Cn);
    mexp_bs6<<<dim3(Tn / 128, Cn / 128, En), 256, 0, stream>>>(hbuf, ewT[0], ewT[1], ewT[2], perm, cnt, pairout, HIDn, Cn, 2);
    combine_k<<<Tn, 256, 0, stream>>>(pairout, topw, x);
  }
  // --- validated bf16 logits tail ---
  rmsnorm_k<<<Tn, 256, 0, stream>>>(x, final_nw, h);
  f2b_k<<<2048, 256, 0, stream>>>(h, hb, NC / 4);
  f2b_k<<<2048, 256, 0, stream>>>(emb, embB, (size_t)Vn * Cn / 4);
  gemm_bt<<<dim3(Tn / 128, Vn / 128), 256, 0, stream>>>(hb, embB, nullptr, out, Tn, Vn, Cn);
}

// Round 11
// 7207.885 us; speedup vs baseline: 1.4936x; 1.4936x over previous
//
#include <hip/hip_runtime.h>
#include <hip/hip_bf16.h>
#include <math.h>

#define Tn   2048
#define Cn   1536
#define Vn   32000
#define NHn  12
#define NKVn 4
#define Dn   128
#define HIDn 2048
#define En   8
#define Kn   2
#define Ln   2
#define NREPn 3
#define EPSn 1e-6f

using bf16 = __hip_bfloat16;
using bf16x8 = __attribute__((ext_vector_type(8))) short;
using f32x4v = __attribute__((ext_vector_type(4))) float;

__device__ __forceinline__ void split3(float v, short& h, short& m, short& lo) {
  bf16 b0 = __float2bfloat16(v);
  float r1 = v - __bfloat162float(b0);
  bf16 b1 = __float2bfloat16(r1);
  float r2 = r1 - __bfloat162float(b1);
  bf16 b2 = __float2bfloat16(r2);
  h = *reinterpret_cast<short*>(&b0);
  m = *reinterpret_cast<short*>(&b1);
  lo = *reinterpret_cast<short*>(&b2);
}
__device__ __forceinline__ float b2f(short s) {
  bf16 b = *reinterpret_cast<bf16*>(&s);
  return __bfloat162float(b);
}
__device__ __forceinline__ void gl_lds16(const void* g, void* l) {
  __builtin_amdgcn_global_load_lds((const __attribute__((address_space(1))) void*)g,
                                   (__attribute__((address_space(3))) void*)l, 16, 0, 0);
}

// ---------------- embed (validated) ----------------
__global__ void embed_k(const int* __restrict__ tok, const float* __restrict__ emb,
                        const float* __restrict__ pos, float* __restrict__ x) {
  int n = blockIdx.x;
  int t = threadIdx.x;
  int id = tok[n];
  const float* er = emb + (size_t)id * Cn;
  const float* pr = pos + (size_t)n * Cn;
  float* xr = x + (size_t)n * Cn;
  for (int c = t; c < Cn; c += 256) xr[c] = er[c] + pr[c];
}

// ---------------- RMSNorm fp32 (validated) ----------------
__global__ void rmsnorm_k(const float* __restrict__ x, const float* __restrict__ w,
                          float* __restrict__ out) {
  int n = blockIdx.x, t = threadIdx.x;
  const float* xr = x + (size_t)n * Cn;
  float v[6];
  float ss = 0.f;
#pragma unroll
  for (int i = 0; i < 6; i++) { v[i] = xr[t + i * 256]; ss += v[i] * v[i]; }
  for (int off = 32; off > 0; off >>= 1) ss += __shfl_down(ss, off, 64);
  __shared__ float red[4];
  __shared__ float rtot;
  int wave = t >> 6, lane = t & 63;
  if (lane == 0) red[wave] = ss;
  __syncthreads();
  if (t == 0) rtot = rsqrtf((red[0] + red[1] + red[2] + red[3]) / (float)Cn + EPSn);
  __syncthreads();
  float r = rtot;
  float* orow = out + (size_t)n * Cn;
#pragma unroll
  for (int i = 0; i < 6; i++) { int c = t + i * 256; orow[c] = v[i] * r * w[c]; }
}

// ---------------- fp32 -> bf16 (validated) ----------------
__global__ void f2b_k(const float* __restrict__ s, bf16* __restrict__ d, size_t n4) {
  size_t i = (size_t)blockIdx.x * 256 + threadIdx.x;
  size_t stride = (size_t)gridDim.x * 256;
  for (; i < n4; i += stride) {
    float4 v = ((const float4*)s)[i];
    d[i * 4 + 0] = __float2bfloat16(v.x);
    d[i * 4 + 1] = __float2bfloat16(v.y);
    d[i * 4 + 2] = __float2bfloat16(v.z);
    d[i * 4 + 3] = __float2bfloat16(v.w);
  }
}

// ---------------- activation split: f32 -> 3x bf16 (flat) ----------------
__global__ void splita_k(const float* __restrict__ s, short* __restrict__ dh,
                         short* __restrict__ dm, short* __restrict__ dl, size_t n4) {
  size_t i = (size_t)blockIdx.x * 256 + threadIdx.x;
  size_t stride = (size_t)gridDim.x * 256;
  for (; i < n4; i += stride) {
    float4 v = ((const float4*)s)[i];
    float a[4] = {v.x, v.y, v.z, v.w};
#pragma unroll
    for (int u = 0; u < 4; u++) {
      short h, m, lo;
      split3(a[u], h, m, lo);
      dh[i * 4 + u] = h; dm[i * 4 + u] = m; dl[i * 4 + u] = lo;
    }
  }
}

// ---------------- transpose + 3-way split: f32 [K,N] -> 3x bf16 [N,K] (batched z) ----------------
__global__ void transp3_k(const float* __restrict__ src, short* __restrict__ dh,
                          short* __restrict__ dm, short* __restrict__ dl, int K, int N) {
  __shared__ __align__(16) float ls[32][33];
  size_t boff = (size_t)blockIdx.z * K * N;
  int k0 = blockIdx.x * 32, n0 = blockIdx.y * 32;
  int t = threadIdx.x;
  int kr = t >> 3, n4 = (t & 7) * 4;
  float4 vv = *(const float4*)&src[boff + (size_t)(k0 + kr) * N + n0 + n4];
  ls[kr][n4 + 0] = vv.x; ls[kr][n4 + 1] = vv.y; ls[kr][n4 + 2] = vv.z; ls[kr][n4 + 3] = vv.w;
  __syncthreads();
  int nr = t >> 3, k4 = (t & 7) * 4;
  size_t dbase = boff + (size_t)(n0 + nr) * K + k0 + k4;
#pragma unroll
  for (int u = 0; u < 4; u++) {
    short h, m, lo;
    split3(ls[k4 + u][nr], h, m, lo);
    dh[dbase + u] = h; dm[dbase + u] = m; dl[dbase + u] = lo;
  }
}

// ---------------- MFMA GEMM pure bf16, Bt [N,K] (validated, logits tail) ----------------
__global__ void __launch_bounds__(256) gemm_bt(const bf16* __restrict__ A, const bf16* __restrict__ Bt,
                                               const float* res, float* Co, int M, int N, int K) {
  int t = threadIdx.x;
  int l = t & 63, w = t >> 6;
  int bm = blockIdx.x * 128, bn = blockIdx.y * 128;
  int wr = (w >> 1) * 64, wc = (w & 1) * 64;
  const f32x4v zero = {0.f, 0.f, 0.f, 0.f};
  f32x4v acc[4][4];
#pragma unroll
  for (int i = 0; i < 4; i++)
#pragma unroll
    for (int j = 0; j < 4; j++) acc[i][j] = zero;
  int rl = l & 15, kg = (l >> 4) * 8;
  const bf16* arow[4];
  const bf16* brow[4];
#pragma unroll
  for (int i = 0; i < 4; i++) arow[i] = A + (size_t)(bm + wr + i * 16 + rl) * K + kg;
#pragma unroll
  for (int j = 0; j < 4; j++) brow[j] = Bt + (size_t)(bn + wc + j * 16 + rl) * K + kg;
  for (int k0 = 0; k0 < K; k0 += 32) {
    bf16x8 a[4], b[4];
#pragma unroll
    for (int i = 0; i < 4; i++) a[i] = *(const bf16x8*)(arow[i] + k0);
#pragma unroll
    for (int j = 0; j < 4; j++) b[j] = *(const bf16x8*)(brow[j] + k0);
#pragma unroll
    for (int i = 0; i < 4; i++)
#pragma unroll
      for (int j = 0; j < 4; j++)
        acc[i][j] = __builtin_amdgcn_mfma_f32_16x16x32_bf16(a[i], b[j], acc[i][j], 0, 0, 0);
  }
#pragma unroll
  for (int i = 0; i < 4; i++) {
    int rbase = bm + wr + i * 16 + (l >> 4) * 4;
#pragma unroll
    for (int j = 0; j < 4; j++) {
      int col = bn + wc + j * 16 + (l & 15);
#pragma unroll
      for (int r = 0; r < 4; r++) {
        size_t idx = (size_t)(rbase + r) * N + col;
        float v = acc[i][j][r];
        if (res) v += res[idx];
        Co[idx] = v;
      }
    }
  }
}

// ---------------- LDS-staged split-fp32 GEMM: pre-split A[M,K] & Bt[N,K] bf16 levels, 6 products ----------------
__global__ void __launch_bounds__(256) gemm6(const bf16* __restrict__ AH, const bf16* __restrict__ AM,
                                             const bf16* __restrict__ AL,
                                             const bf16* __restrict__ BH, const bf16* __restrict__ BM,
                                             const bf16* __restrict__ BL,
                                             const float* res, float* __restrict__ Co,
                                             int M, int N, int K) {
  __shared__ __align__(16) bf16 sAH[128 * 32], sAM[128 * 32], sAL[128 * 32];
  __shared__ __align__(16) bf16 sBH[128 * 32], sBM[128 * 32], sBL[128 * 32];
  int t = threadIdx.x;
  int l = t & 63, w = t >> 6;
  int bm = blockIdx.x * 128, bn = blockIdx.y * 128;
  int wr = (w >> 1) * 64, wc = (w & 1) * 64;
  const f32x4v zero = {0.f, 0.f, 0.f, 0.f};
  f32x4v acc[4][4];
#pragma unroll
  for (int i = 0; i < 4; i++)
#pragma unroll
    for (int j = 0; j < 4; j++) acc[i][j] = zero;
  size_t a0 = (size_t)(bm + (t >> 2)) * K + (t & 3) * 8;
  size_t a1 = (size_t)(bm + 64 + (t >> 2)) * K + (t & 3) * 8;
  size_t b0 = (size_t)(bn + (t >> 2)) * K + (t & 3) * 8;
  size_t b1 = (size_t)(bn + 64 + (t >> 2)) * K + (t & 3) * 8;
  char* l0 = (char*)nullptr;
  int rl = l & 15, ko = (l >> 4) * 8;
  for (int k0 = 0; k0 < K; k0 += 32) {
    gl_lds16(AH + a0 + k0, (char*)sAH + t * 16);
    gl_lds16(AH + a1 + k0, (char*)sAH + (256 + t) * 16);
    gl_lds16(AM + a0 + k0, (char*)sAM + t * 16);
    gl_lds16(AM + a1 + k0, (char*)sAM + (256 + t) * 16);
    gl_lds16(AL + a0 + k0, (char*)sAL + t * 16);
    gl_lds16(AL + a1 + k0, (char*)sAL + (256 + t) * 16);
    gl_lds16(BH + b0 + k0, (char*)sBH + t * 16);
    gl_lds16(BH + b1 + k0, (char*)sBH + (256 + t) * 16);
    gl_lds16(BM + b0 + k0, (char*)sBM + t * 16);
    gl_lds16(BM + b1 + k0, (char*)sBM + (256 + t) * 16);
    gl_lds16(BL + b0 + k0, (char*)sBL + t * 16);
    gl_lds16(BL + b1 + k0, (char*)sBL + (256 + t) * 16);
    __syncthreads();
    bf16x8 aH[4], aM[4], aL[4];
#pragma unroll
    for (int i = 0; i < 4; i++) {
      int ro = (wr + i * 16 + rl) * 32 + ko;
      aH[i] = *(const bf16x8*)(sAH + ro);
      aM[i] = *(const bf16x8*)(sAM + ro);
      aL[i] = *(const bf16x8*)(sAL + ro);
    }
#pragma unroll
    for (int j = 0; j < 4; j++) {
      int ro = (wc + j * 16 + rl) * 32 + ko;
      bf16x8 bh = *(const bf16x8*)(sBH + ro);
      bf16x8 bm_ = *(const bf16x8*)(sBM + ro);
      bf16x8 bl = *(const bf16x8*)(sBL + ro);
#pragma unroll
      for (int i = 0; i < 4; i++) {
        acc[i][j] = __builtin_amdgcn_mfma_f32_16x16x32_bf16(aL[i], bh, acc[i][j], 0, 0, 0);
        acc[i][j] = __builtin_amdgcn_mfma_f32_16x16x32_bf16(aH[i], bl, acc[i][j], 0, 0, 0);
        acc[i][j] = __builtin_amdgcn_mfma_f32_16x16x32_bf16(aM[i], bm_, acc[i][j], 0, 0, 0);
        acc[i][j] = __builtin_amdgcn_mfma_f32_16x16x32_bf16(aM[i], bh, acc[i][j], 0, 0, 0);
        acc[i][j] = __builtin_amdgcn_mfma_f32_16x16x32_bf16(aH[i], bm_, acc[i][j], 0, 0, 0);
        acc[i][j] = __builtin_amdgcn_mfma_f32_16x16x32_bf16(aH[i], bh, acc[i][j], 0, 0, 0);
      }
    }
    __syncthreads();
  }
  (void)l0;
#pragma unroll
  for (int i = 0; i < 4; i++) {
    int rbase = bm + wr + i * 16 + (l >> 4) * 4;
#pragma unroll
    for (int j = 0; j < 4; j++) {
      int col = bn + wc + j * 16 + (l & 15);
#pragma unroll
      for (int r = 0; r < 4; r++) {
        size_t idx = (size_t)(rbase + r) * N + col;
        float v = acc[i][j][r];
        if (res) v += res[idx];
        Co[idx] = v;
      }
    }
  }
}

// ---------------- LDS-staged split-fp32 MoE expert GEMM (gathered A rows) ----------------
// mode 0: store split3(h1) to HH/HM/HL; mode 1: hh = silu(h1)*acc, store split3(hh) in-place;
// mode 2: Co = acc (pairout).
__global__ void __launch_bounds__(256) mexp6(const bf16* __restrict__ AH, const bf16* __restrict__ AM,
                                             const bf16* __restrict__ AL,
                                             const bf16* __restrict__ BH, const bf16* __restrict__ BM,
                                             const bf16* __restrict__ BL,
                                             const int* __restrict__ perm, const int* __restrict__ cnt,
                                             int ebase,
                                             short* __restrict__ HH, short* __restrict__ HM,
                                             short* __restrict__ HL,
                                             float* __restrict__ Co, int K, int N, int mode) {
  int e = ebase + blockIdx.z;
  int nrows = cnt[e];
  int bm = blockIdx.x * 128;
  if (bm >= nrows) return;
  int bn = blockIdx.y * 128;
  size_t eoff = (size_t)blockIdx.z * K * N;  // within current half's transposed buffers
  __shared__ __align__(16) bf16 sAH[128 * 32], sAM[128 * 32], sAL[128 * 32];
  __shared__ __align__(16) bf16 sBH[128 * 32], sBM[128 * 32], sBL[128 * 32];
  __shared__ int prow[128];
  int t = threadIdx.x, l = t & 63, w = t >> 6;
  if (t < 128) {
    int i = bm + t;
    prow[t] = (i < nrows) ? perm[e * Tn + i] : -1;
  }
  __syncthreads();
  int wr = (w >> 1) * 64, wc = (w & 1) * 64;
  const f32x4v zero = {0.f, 0.f, 0.f, 0.f};
  f32x4v acc[4][4];
#pragma unroll
  for (int i = 0; i < 4; i++)
#pragma unroll
    for (int j = 0; j < 4; j++) acc[i][j] = zero;
  int p0 = prow[t >> 2], p1 = prow[64 + (t >> 2)];
  int g0r = (p0 >= 0) ? (mode == 2 ? p0 : (p0 >> 1)) : 0;
  int g1r = (p1 >= 0) ? (mode == 2 ? p1 : (p1 >> 1)) : 0;
  size_t a0 = (size_t)g0r * K + (t & 3) * 8;
  size_t a1 = (size_t)g1r * K + (t & 3) * 8;
  size_t b0 = eoff + (size_t)(bn + (t >> 2)) * K + (t & 3) * 8;
  size_t b1 = eoff + (size_t)(bn + 64 + (t >> 2)) * K + (t & 3) * 8;
  int rl = l & 15, ko = (l >> 4) * 8;
  for (int k0 = 0; k0 < K; k0 += 32) {
    gl_lds16(AH + a0 + k0, (char*)sAH + t * 16);
    gl_lds16(AH + a1 + k0, (char*)sAH + (256 + t) * 16);
    gl_lds16(AM + a0 + k0, (char*)sAM + t * 16);
    gl_lds16(AM + a1 + k0, (char*)sAM + (256 + t) * 16);
    gl_lds16(AL + a0 + k0, (char*)sAL + t * 16);
    gl_lds16(AL + a1 + k0, (char*)sAL + (256 + t) * 16);
    gl_lds16(BH + b0 + k0, (char*)sBH + t * 16);
    gl_lds16(BH + b1 + k0, (char*)sBH + (256 + t) * 16);
    gl_lds16(BM + b0 + k0, (char*)sBM + t * 16);
    gl_lds16(BM + b1 + k0, (char*)sBM + (256 + t) * 16);
    gl_lds16(BL + b0 + k0, (char*)sBL + t * 16);
    gl_lds16(BL + b1 + k0, (char*)sBL + (256 + t) * 16);
    __syncthreads();
    bf16x8 aH[4], aM[4], aL[4];
#pragma unroll
    for (int i = 0; i < 4; i++) {
      int ro = (wr + i * 16 + rl) * 32 + ko;
      aH[i] = *(const bf16x8*)(sAH + ro);
      aM[i] = *(const bf16x8*)(sAM + ro);
      aL[i] = *(const bf16x8*)(sAL + ro);
    }
#pragma unroll
    for (int j = 0; j < 4; j++) {
      int ro = (wc + j * 16 + rl) * 32 + ko;
      bf16x8 bh = *(const bf16x8*)(sBH + ro);
      bf16x8 bm_ = *(const bf16x8*)(sBM + ro);
      bf16x8 bl = *(const bf16x8*)(sBL + ro);
#pragma unroll
      for (int i = 0; i < 4; i++) {
        acc[i][j] = __builtin_amdgcn_mfma_f32_16x16x32_bf16(aL[i], bh, acc[i][j], 0, 0, 0);
        acc[i][j] = __builtin_amdgcn_mfma_f32_16x16x32_bf16(aH[i], bl, acc[i][j], 0, 0, 0);
        acc[i][j] = __builtin_amdgcn_mfma_f32_16x16x32_bf16(aM[i], bm_, acc[i][j], 0, 0, 0);
        acc[i][j] = __builtin_amdgcn_mfma_f32_16x16x32_bf16(aM[i], bh, acc[i][j], 0, 0, 0);
        acc[i][j] = __builtin_amdgcn_mfma_f32_16x16x32_bf16(aH[i], bm_, acc[i][j], 0, 0, 0);
        acc[i][j] = __builtin_amdgcn_mfma_f32_16x16x32_bf16(aH[i], bh, acc[i][j], 0, 0, 0);
      }
    }
    __syncthreads();
  }
#pragma unroll
  for (int i = 0; i < 4; i++) {
#pragma unroll
    for (int r = 0; r < 4; r++) {
      int lrow = wr + i * 16 + (l >> 4) * 4 + r;
      int p = prow[lrow];
      if (p < 0) continue;
#pragma unroll
      for (int j = 0; j < 4; j++) {
        int col = bn + wc + j * 16 + (l & 15);
        size_t idx = (size_t)p * N + col;
        float v = acc[i][j][r];
        if (mode == 0) {
          short h, m, lo;
          split3(v, h, m, lo);
          HH[idx] = h; HM[idx] = m; HL[idx] = lo;
        } else if (mode == 1) {
          float v1 = b2f(HH[idx]) + b2f(HM[idx]) + b2f(HL[idx]);
          float hh = (v1 / (1.f + expf(-v1))) * v;
          short h, m, lo;
          split3(hh, h, m, lo);
          HH[idx] = h; HM[idx] = m; HL[idx] = lo;
        } else {
          Co[idx] = v;
        }
      }
    }
  }
}

// ---------------- register-resident fp32 flash attention (validated; long blocks first) ----------------
__global__ void __launch_bounds__(256) attn_fast_k(const float* __restrict__ q,
                                                   const float* __restrict__ k,
                                                   const float* __restrict__ v,
                                                   float* __restrict__ y) {
  int qt = gridDim.x - 1 - blockIdx.x;  // schedule long (large-qt) blocks first
  int head = blockIdx.y;
  int kvh = head / NREPn;
  int q0 = qt * 32;
  int t = threadIdx.x;
  int r = t >> 3, g = t & 7, d0 = g * 16;
  __shared__ __align__(16) float ks[32][Dn + 4];
  __shared__ __align__(16) float vs[32][Dn + 4];
  const float scale = 0.08838834764831845f;
  float qr[16];
  {
    const float* qrow = q + (size_t)(q0 + r) * (NHn * Dn) + head * Dn + d0;
#pragma unroll
    for (int j = 0; j < 16; j += 4) {
      float4 u = *(const float4*)(qrow + j);
      qr[j] = u.x * scale; qr[j + 1] = u.y * scale;
      qr[j + 2] = u.z * scale; qr[j + 3] = u.w * scale;
    }
  }
  float o[16];
#pragma unroll
  for (int j = 0; j < 16; j++) o[j] = 0.f;
  float rowm = -1e30f, rowl = 0.f;

  for (int kt = 0; kt <= qt; kt++) {
    int kv0 = kt * 32;
    for (int e = t; e < 32 * 32; e += 256) {
      int rr = e >> 5, c4 = (e & 31) * 4;
      size_t off = (size_t)(kv0 + rr) * (NKVn * Dn) + kvh * Dn + c4;
      *(float4*)&ks[rr][c4] = *(const float4*)(k + off);
      *(float4*)&vs[rr][c4] = *(const float4*)(v + off);
    }
    __syncthreads();
    float s[32];
#pragma unroll
    for (int kk = 0; kk < 32; kk++) {
      const float* krow = &ks[kk][d0];
      float p = 0.f;
#pragma unroll
      for (int j = 0; j < 16; j += 4) {
        float4 u = *(const float4*)(krow + j);
        p += qr[j] * u.x + qr[j + 1] * u.y + qr[j + 2] * u.z + qr[j + 3] * u.w;
      }
      p += __shfl_xor(p, 1);
      p += __shfl_xor(p, 2);
      p += __shfl_xor(p, 4);
      s[kk] = p;
    }
    if (kt == qt) {
#pragma unroll
      for (int kk = 0; kk < 32; kk++)
        if (kk > r) s[kk] = -1e30f;
    }
    float mx = s[0];
#pragma unroll
    for (int kk = 1; kk < 32; kk++) mx = fmaxf(mx, s[kk]);
    float m_new = fmaxf(rowm, mx);
    float corr = expf(rowm - m_new);
    float sum = 0.f;
#pragma unroll
    for (int kk = 0; kk < 32; kk++) { s[kk] = expf(s[kk] - m_new); sum += s[kk]; }
    rowl = rowl * corr + sum;
    rowm = m_new;
#pragma unroll
    for (int j = 0; j < 16; j++) o[j] *= corr;
#pragma unroll
    for (int kk = 0; kk < 32; kk++) {
      float p = s[kk];
      const float* vrow = &vs[kk][d0];
#pragma unroll
      for (int j = 0; j < 16; j += 4) {
        float4 u = *(const float4*)(vrow + j);
        o[j] += p * u.x; o[j + 1] += p * u.y; o[j + 2] += p * u.z; o[j + 3] += p * u.w;
      }
    }
    __syncthreads();
  }
  float inv = 1.f / rowl;
  float* yrow = y + (size_t)(q0 + r) * (NHn * Dn) + head * Dn + d0;
#pragma unroll
  for (int j = 0; j < 16; j += 4) {
    float4 u;
    u.x = o[j] * inv; u.y = o[j + 1] * inv; u.z = o[j + 2] * inv; u.w = o[j + 3] * inv;
    *(float4*)(yrow + j) = u;
  }
}

// ---------------- gate logits (validated) ----------------
__global__ void gate_k(const float* __restrict__ xf, const float* __restrict__ g,
                       float* __restrict__ gl) {
  int n = blockIdx.x, t = threadIdx.x;
  int e = t & 7, cs = t >> 3;
  const float* xr = xf + (size_t)n * Cn;
  float s = 0.f;
  for (int j = 0; j < Cn / 32; j++) {
    int c = cs + 32 * j;
    s += xr[c] * g[c * En + e];
  }
  __shared__ float red[256];
  red[t] = s;
  __syncthreads();
  if (t < 8) {
    float tot = 0.f;
    for (int j = 0; j < 32; j++) tot += red[t + 8 * j];
    gl[n * En + t] = tot;
  }
}

// ---------------- routing (validated, Tn stride) ----------------
__global__ void route_k(const float* __restrict__ gl, float* __restrict__ topw,
                        int* __restrict__ cnt, int* __restrict__ perm) {
  int n = blockIdx.x * blockDim.x + threadIdx.x;
  if (n >= Tn) return;
  float p[En];
  float mx = -1e30f;
#pragma unroll
  for (int e = 0; e < En; e++) { p[e] = gl[n * En + e]; mx = fmaxf(mx, p[e]); }
  float s = 0.f;
#pragma unroll
  for (int e = 0; e < En; e++) { p[e] = expf(p[e] - mx); s += p[e]; }
  float invs = 1.f / s;
#pragma unroll
  for (int e = 0; e < En; e++) p[e] *= invs;
  int i0 = 0;
#pragma unroll
  for (int e = 1; e < En; e++) if (p[e] > p[i0]) i0 = e;
  int i1 = (i0 == 0) ? 1 : 0;
#pragma unroll
  for (int e = 0; e < En; e++) if (e != i0 && p[e] > p[i1]) i1 = e;
  float w0 = p[i0], w1 = p[i1], sw = w0 + w1;
  topw[2 * n]     = w0 / sw;
  topw[2 * n + 1] = w1 / sw;
  int pos0 = atomicAdd(&cnt[i0], 1);
  perm[i0 * Tn + pos0] = 2 * n;
  int pos1 = atomicAdd(&cnt[i1], 1);
  perm[i1 * Tn + pos1] = 2 * n + 1;
}

// ---------------- combine (validated) ----------------
__global__ void combine_k(const float* __restrict__ pairout, const float* __restrict__ topw,
                          float* __restrict__ x) {
  int n = blockIdx.x, t = threadIdx.x;
  float w0 = topw[2 * n], w1 = topw[2 * n + 1];
  const float* p0 = pairout + (size_t)(2 * n) * Cn;
  const float* p1 = pairout + (size_t)(2 * n + 1) * Cn;
  float* xr = x + (size_t)n * Cn;
  for (int c = t; c < Cn; c += 256) xr[c] += w0 * p0[c] + w1 * p1[c];
}

// =================================================================================
extern "C" void kernel_launch(void* const* d_in, const int* in_sizes, int n_in,
                              void* d_out, int out_size, void* d_ws, size_t ws_size,
                              hipStream_t stream) {
  const int*   tokens = (const int*)d_in[0];
  const float* emb    = (const float*)d_in[1];
  const float* pos    = (const float*)d_in[2];
  const float* wq     = (const float*)d_in[3];
  const float* wk     = (const float*)d_in[4];
  const float* wv     = (const float*)d_in[5];
  const float* wo     = (const float*)d_in[6];
  const float* attn_nw= (const float*)d_in[7];
  const float* ffn_nw = (const float*)d_in[8];
  const float* gate   = (const float*)d_in[9];
  const float* ew1    = (const float*)d_in[10];
  const float* ew2    = (const float*)d_in[11];
  const float* ew3    = (const float*)d_in[12];
  const float* final_nw = (const float*)d_in[13];
  float* out = (float*)d_out;

  char* wsb = (char*)d_ws;
  const size_t NC = (size_t)Tn * Cn;
  size_t off = 0;
  auto alloc = [&](size_t bytes) -> size_t {
    off = (off + 255) & ~(size_t)255;
    size_t p = off;
    off += bytes;
    return p;
  };
  // Total ~183 MB (proven budget >= 250 MB from round 10).
  size_t o_x    = alloc(NC * 4);
  size_t o_h    = alloc(NC * 4);
  size_t o_gl   = alloc((size_t)Tn * En * 4);
  size_t o_topw = alloc((size_t)Tn * Kn * 4);
  size_t o_cnt  = alloc(64);
  size_t o_perm = alloc((size_t)En * Tn * 4);
  // W region: 3 levels x (4 experts x Cn x HIDn) bf16 = 75.5 MB; attn splits packed at front
  size_t wlvl   = (size_t)4 * Cn * HIDn * 2;          // 25.17 MB
  size_t o_w    = alloc(3 * wlvl);
  // S region
  size_t hs_lvl = NC * 2;                              // 6.29 MB
  size_t o_hs   = alloc(3 * hs_lvl);                   // activation splits (h / yb reuse)
  size_t o_qb   = alloc(NC * 4);
  size_t o_kb   = alloc((size_t)Tn * NKVn * Dn * 4);
  size_t o_vb   = alloc((size_t)Tn * NKVn * Dn * 4);
  size_t o_yb   = alloc(NC * 4);
  size_t hb_lvl = (size_t)Tn * Kn * HIDn * 2;          // 16.78 MB
  // hbuf splits alias qb..yb (dead in MoE) + extra
  size_t o_hbs  = o_qb;
  size_t end_hbs = o_hbs + 3 * hb_lvl;
  if (off < end_hbs) off = end_hbs;
  size_t o_pair = alloc(NC * 4);                       // pairout (also hb alias at tail)

  float* x       = (float*)(wsb + o_x);
  float* h       = (float*)(wsb + o_h);
  float* gl      = (float*)(wsb + o_gl);
  float* topw    = (float*)(wsb + o_topw);
  int*   cnt     = (int*)(wsb + o_cnt);
  int*   perm    = (int*)(wsb + o_perm);
  float* qb      = (float*)(wsb + o_qb);
  float* kb      = (float*)(wsb + o_kb);
  float* vb      = (float*)(wsb + o_vb);
  float* yb      = (float*)(wsb + o_yb);
  float* pairout = (float*)(wsb + o_pair);
  bf16*  hb      = (bf16*)(wsb + o_pair);              // tail alias (pairout dead)
  bf16*  embB    = (bf16*)(wsb + o_w);                 // tail alias (weights dead); 98.3MB spans W+start of S

  short* hs[3]; short* hbs[3]; short* ewT[3];
  for (int s = 0; s < 3; s++) {
    hs[s]  = (short*)(wsb + o_hs + (size_t)s * hs_lvl);
    hbs[s] = (short*)(wsb + o_hbs + (size_t)s * hb_lvl);
    ewT[s] = (short*)(wsb + o_w + (size_t)s * wlvl);
  }
  // attn weight splits packed at front of W (dead when ewT in use, per-layer refresh)
  size_t wq_lvl = (size_t)Cn * (NHn * Dn) * 2;         // 4.72 MB
  size_t wk_lvl = (size_t)Cn * (NKVn * Dn) * 2;        // 1.57 MB
  short* wqT[3]; short* wkT[3]; short* wvT[3]; short* woT[3];
  {
    size_t p = o_w;
    for (int s = 0; s < 3; s++) { wqT[s] = (short*)(wsb + p); p += wq_lvl; }
    for (int s = 0; s < 3; s++) { wkT[s] = (short*)(wsb + p); p += wk_lvl; }
    for (int s = 0; s < 3; s++) { wvT[s] = (short*)(wsb + p); p += wk_lvl; }
    for (int s = 0; s < 3; s++) { woT[s] = (short*)(wsb + p); p += wq_lvl; }
  }

  embed_k<<<Tn, 256, 0, stream>>>(tokens, emb, pos, x);
  for (int l = 0; l < Ln; l++) {
    const float* wq_l = wq + (size_t)l * Cn * (NHn * Dn);
    const float* wk_l = wk + (size_t)l * Cn * (NKVn * Dn);
    const float* wv_l = wv + (size_t)l * Cn * (NKVn * Dn);
    const float* wo_l = wo + (size_t)l * Cn * Cn;
    const float* g_l  = gate + (size_t)l * Cn * En;
    const float* e1_l = ew1 + (size_t)l * En * Cn * HIDn;
    const float* e2_l = ew2 + (size_t)l * En * HIDn * Cn;
    const float* e3_l = ew3 + (size_t)l * En * Cn * HIDn;

    // --- attention ---
    transp3_k<<<dim3(Cn / 32, (NHn * Dn) / 32, 1), 256, 0, stream>>>(wq_l, wqT[0], wqT[1], wqT[2], Cn, NHn * Dn);
    transp3_k<<<dim3(Cn / 32, (NKVn * Dn) / 32, 1), 256, 0, stream>>>(wk_l, wkT[0], wkT[1], wkT[2], Cn, NKVn * Dn);
    transp3_k<<<dim3(Cn / 32, (NKVn * Dn) / 32, 1), 256, 0, stream>>>(wv_l, wvT[0], wvT[1], wvT[2], Cn, NKVn * Dn);
    transp3_k<<<dim3(Cn / 32, Cn / 32, 1), 256, 0, stream>>>(wo_l, woT[0], woT[1], woT[2], Cn, Cn);
    rmsnorm_k<<<Tn, 256, 0, stream>>>(x, attn_nw + (size_t)l * Cn, h);
    splita_k<<<2048, 256, 0, stream>>>(h, hs[0], hs[1], hs[2], NC / 4);
    gemm6<<<dim3(Tn / 128, (NHn * Dn) / 128), 256, 0, stream>>>(
        (bf16*)hs[0], (bf16*)hs[1], (bf16*)hs[2], (bf16*)wqT[0], (bf16*)wqT[1], (bf16*)wqT[2],
        nullptr, qb, Tn, NHn * Dn, Cn);
    gemm6<<<dim3(Tn / 128, (NKVn * Dn) / 128), 256, 0, stream>>>(
        (bf16*)hs[0], (bf16*)hs[1], (bf16*)hs[2], (bf16*)wkT[0], (bf16*)wkT[1], (bf16*)wkT[2],
        nullptr, kb, Tn, NKVn * Dn, Cn);
    gemm6<<<dim3(Tn / 128, (NKVn * Dn) / 128), 256, 0, stream>>>(
        (bf16*)hs[0], (bf16*)hs[1], (bf16*)hs[2], (bf16*)wvT[0], (bf16*)wvT[1], (bf16*)wvT[2],
        nullptr, vb, Tn, NKVn * Dn, Cn);
    attn_fast_k<<<dim3(Tn / 32, NHn), 256, 0, stream>>>(qb, kb, vb, yb);
    splita_k<<<2048, 256, 0, stream>>>(yb, hs[0], hs[1], hs[2], NC / 4);
    gemm6<<<dim3(Tn / 128, Cn / 128), 256, 0, stream>>>(
        (bf16*)hs[0], (bf16*)hs[1], (bf16*)hs[2], (bf16*)woT[0], (bf16*)woT[1], (bf16*)woT[2],
        x, x, Tn, Cn, Cn);

    // --- MoE ---
    rmsnorm_k<<<Tn, 256, 0, stream>>>(x, ffn_nw + (size_t)l * Cn, h);
    gate_k<<<Tn, 256, 0, stream>>>(h, g_l, gl);
    hipMemsetAsync(cnt, 0, 64, stream);
    route_k<<<Tn / 256, 256, 0, stream>>>(gl, topw, cnt, perm);
    splita_k<<<2048, 256, 0, stream>>>(h, hs[0], hs[1], hs[2], NC / 4);
    for (int half = 0; half < 2; half++) {
      size_t hoff = (size_t)half * 4 * Cn * HIDn;
      int eb = half * 4;
      transp3_k<<<dim3(Cn / 32, HIDn / 32, 4), 256, 0, stream>>>(e1_l + hoff, ewT[0], ewT[1], ewT[2], Cn, HIDn);
      mexp6<<<dim3(Tn / 128, HIDn / 128, 4), 256, 0, stream>>>(
          (bf16*)hs[0], (bf16*)hs[1], (bf16*)hs[2], (bf16*)ewT[0], (bf16*)ewT[1], (bf16*)ewT[2],
          perm, cnt, eb, hbs[0], hbs[1], hbs[2], nullptr, Cn, HIDn, 0);
      transp3_k<<<dim3(Cn / 32, HIDn / 32, 4), 256, 0, stream>>>(e3_l + hoff, ewT[0], ewT[1], ewT[2], Cn, HIDn);
      mexp6<<<dim3(Tn / 128, HIDn / 128, 4), 256, 0, stream>>>(
          (bf16*)hs[0], (bf16*)hs[1], (bf16*)hs[2], (bf16*)ewT[0], (bf16*)ewT[1], (bf16*)ewT[2],
          perm, cnt, eb, hbs[0], hbs[1], hbs[2], nullptr, Cn, HIDn, 1);
      transp3_k<<<dim3(HIDn / 32, Cn / 32, 4), 256, 0, stream>>>(e2_l + hoff, ewT[0], ewT[1], ewT[2], HIDn, Cn);
      mexp6<<<dim3(Tn / 128, Cn / 128, 4), 256, 0, stream>>>(
          (bf16*)hbs[0], (bf16*)hbs[1], (bf16*)hbs[2], (bf16*)ewT[0], (bf16*)ewT[1], (bf16*)ewT[2],
          perm, cnt, eb, hbs[0], hbs[1], hbs[2], pairout, HIDn, Cn, 2);
    }
    combine_k<<<Tn, 256, 0, stream>>>(pairout, topw, x);
  }
  // --- validated bf16 logits tail ---
  rmsnorm_k<<<Tn, 256, 0, stream>>>(x, final_nw, h);
  f2b_k<<<2048, 256, 0, stream>>>(h, hb, NC / 4);
  f2b_k<<<2048, 256, 0, stream>>>(emb, embB, (size_t)Vn * Cn / 4);
  gemm_bt<<<dim3(Tn / 128, Vn / 128), 256, 0, stream>>>(hb, embB, nullptr, out, Tn, Vn, Cn);
}